// Round 11
// baseline (207.692 us; speedup 1.0000x reference)
//
#include <hip/hip_runtime.h>
#include <hip/hip_fp16.h>
#include <hip/hip_bf16.h>
#include <stdint.h>

#define WN 343       // tokens per window
#define NH 6         // heads
#define HD 32        // head dim
#define CD 192       // channels
#define NB 128       // windows (batch)
#define NWM 32       // mask windows
#define BMROW 352            // padded query dim
#define BMSLICE (11*16*BMROW) // dwords per slice = 61952
#define BMKC (16*BMROW)       // dwords per kc chunk = 5632
#define LOG2E 1.4426950408889634f
#define XTS 2064     // X LDS tile stride in shorts (64*32 + 16 stagger)

typedef __attribute__((ext_vector_type(8))) short short8;
typedef __attribute__((ext_vector_type(4))) float f32x4;

__device__ __forceinline__ unsigned short f2bf(float f) {
  union { float f; uint32_t u; } v; v.f = f;
  uint32_t r = v.u + 0x7fffu + ((v.u >> 16) & 1u);
  return (unsigned short)(r >> 16);
}

// packed f32x2 -> bf16x2 (v_cvt_pk_bf16_f32 on gfx950); low half = a
__device__ __forceinline__ uint32_t pk2bf(float a, float b) {
  __hip_bfloat162 h = __float22bfloat162_rn(make_float2(a, b));
  return *(uint32_t*)&h;
}

__device__ __forceinline__ uint32_t pkh2(float a, float b) {
  __half2 h; h.x = __float2half(a); h.y = __float2half(b);
  return *(uint32_t*)&h;
}

// async global->LDS, 16B per lane; LDS dest is wave-uniform base + lane*16
typedef const __attribute__((address_space(1))) unsigned int* gas_ptr;
typedef __attribute__((address_space(3))) unsigned int* las_ptr;
__device__ __forceinline__ void gload16(const unsigned short* g, unsigned short* l) {
  __builtin_amdgcn_global_load_lds((gas_ptr)(const void*)g, (las_ptr)(void*)l, 16, 0, 0);
}

// 2-phase pipeline barrier (T3 minimal): manual vmcnt drain + RAW s_barrier.
// sched_barrier(0) fences (rule #18: hipcc hoists past inline asm).
__device__ __forceinline__ void pipe_bar() {
  asm volatile("s_waitcnt vmcnt(0) lgkmcnt(0)" ::: "memory");
  __builtin_amdgcn_sched_barrier(0);
  __builtin_amdgcn_s_barrier();
  __builtin_amdgcn_sched_barrier(0);
}

// ---------------- prep (r9 structure, unchanged): bias gather (264) | mask
// repack LDS-free (352) | wq swizzle (54) | wp swizzle (18). Static LDS only
// M[88][33] (11.6KB). bias/mask pre-scaled log2(e); OOB keys: bias=-30000
// (exp2->0), mask=0. rpb gather once per (h,kc,rowgroup) -- never per wdx.
__global__ __launch_bounds__(256) void prep_kernel(
    const float* __restrict__ wq, const float* __restrict__ wp,
    unsigned short* __restrict__ wqb, unsigned short* __restrict__ wpb,
    const int* __restrict__ rel, const float* __restrict__ rpb,
    const float* __restrict__ mask, uint32_t* __restrict__ bP,
    uint32_t* __restrict__ mP) {
  __shared__ float M[88][33];   // bias branch only, 11.6KB
  const int bid = blockIdx.x;
  const int tid = threadIdx.x;
  if (bid < 264) {
    // bias gather: 66 (h,kc) pairs x 4 row-groups of 88
    const int h = bid / 44;
    const int rem = bid - h * 44;
    const int kc = rem >> 2;
    const int g = rem & 3;
    const int n0 = g * 88;
    const int k0 = kc * 32;
    for (int idx = tid; idx < 88 * 32; idx += 256) {
      int nl = idx >> 5, k = idx & 31;
      int n = n0 + nl;
      int nc = (n < WN) ? n : (WN - 1);
      M[nl][k] = (k0 + k < WN) ? rpb[rel[nc * WN + k0 + k] * NH + h] * LOG2E
                               : -30000.0f;
    }
    __syncthreads();
    uint32_t* outp = bP + (size_t)h * BMSLICE + (size_t)kc * BMKC;
    if (tid < 88) {
      const int nl = tid;
      const int n = n0 + nl;
#pragma unroll
      for (int quad = 0; quad < 4; ++quad) {
        uint4 o;
        o.x = pkh2(M[nl][quad * 8 + 0], M[nl][quad * 8 + 4]);
        o.y = pkh2(M[nl][quad * 8 + 1], M[nl][quad * 8 + 5]);
        o.z = pkh2(M[nl][quad * 8 + 2], M[nl][quad * 8 + 6]);
        o.w = pkh2(M[nl][quad * 8 + 3], M[nl][quad * 8 + 7]);
        *(uint4*)(outp + ((size_t)quad * 352 + n) * 4) = o;
      }
    }
    return;
  }
  int cb = bid - 264;
  if (cb < 352) {
    // mask repack, LDS-free
    const int wdx = cb / 11;
    const int kc = cb - wdx * 11;
    const int k0 = kc * 32;
    const float* mw = mask + (size_t)wdx * (WN * WN);
    uint32_t* outp = mP + (size_t)wdx * BMSLICE + (size_t)kc * BMKC;
#pragma unroll
    for (int quad = 0; quad < 4; ++quad) {
      const int q8 = quad * 8;
#pragma unroll
      for (int j = 0; j < 2; ++j) {
        int n = tid + 256 * j;
        if (n < 352) {
          float v[8];
#pragma unroll
          for (int i = 0; i < 8; ++i) {
            int kk = k0 + q8 + i;
            v[i] = (n < WN && kk < WN) ? mw[n * WN + kk] * LOG2E : 0.0f;
          }
          uint4 o;
          o.x = pkh2(v[0], v[4]);
          o.y = pkh2(v[1], v[5]);
          o.z = pkh2(v[2], v[6]);
          o.w = pkh2(v[3], v[7]);
          *(uint4*)(outp + ((size_t)quad * 352 + n) * 4) = o;
        }
      }
    }
    return;
  }
  cb -= 352;
  if (cb < 54) {
    // wq -> swizzled bf16 tiles: 18 tiles (s*6+kt) x 192 rows x 4 chunks
    int g = cb * 256 + tid;            // < 13824
    int sk = g / 768; int rem = g - sk * 768;
    int row = rem >> 2; int cc = rem & 3;
    int s = sk / 6; int kt = sk - s * 6;
    int lch = cc ^ ((row >> 1) & 3);
    const float* src = wq + (size_t)(s * 192 + row) * CD + kt * 32 + lch * 8;
    f32x4 a = *(const f32x4*)src;
    f32x4 b = *(const f32x4*)(src + 4);
    union { short8 v8; uint32_t d[4]; } pk;
    pk.d[0] = pk2bf(a[0], a[1]);
    pk.d[1] = pk2bf(a[2], a[3]);
    pk.d[2] = pk2bf(b[0], b[1]);
    pk.d[3] = pk2bf(b[2], b[3]);
    *(short8*)(wqb + (size_t)g * 8) = pk.v8;
    return;
  }
  cb -= 54;
  // wp -> swizzled bf16 tiles: 6 tiles (kt) x 192 rows x 4 chunks
  int g = cb * 256 + tid;            // < 4608
  int kt = g / 768; int rem = g - kt * 768;
  int row = rem >> 2; int cc = rem & 3;
  int lch = cc ^ ((row >> 1) & 3);
  const float* src = wp + (size_t)row * CD + kt * 32 + lch * 8;
  f32x4 a = *(const f32x4*)src;
  f32x4 b = *(const f32x4*)(src + 4);
  union { short8 v8; uint32_t d[4]; } pk;
  pk.d[0] = pk2bf(a[0], a[1]);
  pk.d[1] = pk2bf(a[2], a[3]);
  pk.d[2] = pk2bf(b[0], b[1]);
  pk.d[3] = pk2bf(b[2], b[3]);
  *(short8*)(wpb + (size_t)g * 8) = pk.v8;
}

// ---------------- QKV GEMM (r11): 64 rows x ALL 3 slices, grid 686.
// r10's 128-row/grid-343 version left 169 CUs with ONE resident block
// (Occupancy 11%) -- every pipe_bar stalled the whole CU. 64-row tiles:
// LDS 48.2KB (X 24.2 + W dbuf 24) -> 3 blocks/CU, 686 blocks = 2.7/CU avg
// -> cross-block overlap hides W-DMA + store latency. X still read ONCE
// (33.7MB); W re-reads 151MB but pure L2 (221KB resident). Same 2-phase
// pipe_bar pipeline; epilogue repack overlays the W dbuf region.
__global__ __launch_bounds__(256) void qkv_kernel(
    const float* __restrict__ x, const unsigned short* __restrict__ wqb,
    const float* __restrict__ bvec,
    unsigned short* __restrict__ qb, unsigned short* __restrict__ kb,
    unsigned short* __restrict__ vb) {
  __shared__ __align__(16) unsigned short SL[6 * XTS + 2 * 6144];  // 48.2KB
  unsigned short* B0 = SL + 6 * XTS;
  unsigned short* B1 = B0 + 6144;
  const int tid = threadIdx.x;
  const int wave = tid >> 6, lane = tid & 63;
  const int quad = lane >> 4, c = lane & 15;
  const int m0 = blockIdx.x * 64;
  const int chk = (quad ^ ((c >> 1) & 3)) * 8;

  auto WSTAGE = [&](unsigned short* buf, int s, int kt) {
    const unsigned short* gw = wqb + ((size_t)s * 6 + kt) * 6144 + tid * 8;
    unsigned short* lw = buf + (size_t)wave * 512;
    gload16(gw, lw);
    gload16(gw + 2048, lw + 2048);
    gload16(gw + 4096, lw + 4096);
  };

  // stage W(0,0) DMA first (overlaps the X cvt), then X once: 64x192
  // fp32 -> bf16 into per-kt tiles [64][32] with XOR-swizzled 16B chunks
  WSTAGE(B0, 0, 0);
#pragma unroll
  for (int it = 0; it < 6; ++it) {
    int u = tid + 256 * it;              // < 1536
    int lrow = u / 24, c24 = u - lrow * 24;
    int kt = c24 >> 2, j = c24 & 3;
    const float* src = x + (size_t)(m0 + lrow) * CD + kt * 32 + j * 8;
    f32x4 a = *(const f32x4*)src;
    f32x4 b = *(const f32x4*)(src + 4);
    union { short8 v8; uint32_t d[4]; } pk;
    pk.d[0] = pk2bf(a[0], a[1]);
    pk.d[1] = pk2bf(a[2], a[3]);
    pk.d[2] = pk2bf(b[0], b[1]);
    pk.d[3] = pk2bf(b[2], b[3]);
    int cw = (j ^ ((lrow >> 1) & 3)) * 8;
    *(short8*)&SL[kt * XTS + lrow * 32 + cw] = pk.v8;
  }
  pipe_bar();

  // q scale folded with log2(e): 32^-0.5 * 1.4426950409 (softmax runs in
  // exp2 domain; bias/mask pre-scaled by log2(e) in prep)
  const float qscale = 0.25503486f;
  f32x4 acc[12];
  // repack overlays the W dbuf region; stride 36 shorts -> all-32-bank
  unsigned short* Lh0 = B0;            // 64 rows x 36
  unsigned short* Lh1 = B0 + 2304;

  for (int s = 0; s < 3; ++s) {
#pragma unroll
    for (int j = 0; j < 12; ++j) acc[j] = (f32x4){0.f, 0.f, 0.f, 0.f};

    for (int kt = 0; kt < 6; ++kt) {
      unsigned short* cur = (kt & 1) ? B1 : B0;
      unsigned short* nxt = (kt & 1) ? B0 : B1;
      if (kt < 5) WSTAGE(nxt, s, kt + 1);   // issue next W while computing
      const unsigned short* XLb = SL + kt * XTS;
      short8 af = *(const short8*)&XLb[(wave * 16 + c) * 32 + chk];
#pragma unroll
      for (int j = 0; j < 12; ++j) {
        short8 bfr = *(const short8*)&cur[(j * 16 + c) * 32 + chk];
        acc[j] = __builtin_amdgcn_mfma_f32_16x16x32_bf16(af, bfr, acc[j], 0, 0, 0);
      }
      pipe_bar();
    }

    // epilogue for slice s (repack buffers live in the W dbuf region)
    unsigned short* dst = (s == 0) ? qb : ((s == 1) ? kb : vb);
    const float scl = (s == 0) ? qscale : 1.0f;
    const int n0 = s * 192;
    for (int hh = 0; hh < 3; ++hh) {
      __syncthreads();
#pragma unroll
      for (int jj = 0; jj < 4; ++jj) {
        int j = hh * 4 + jj;
        int hl = jj >> 1;
        int dd = (jj & 1) * 16 + c;
        float bn = bvec[n0 + j * 16 + c];
        unsigned short* L = hl ? Lh1 : Lh0;
#pragma unroll
        for (int r = 0; r < 4; ++r) {
          int m = wave * 16 + quad * 4 + r;
          L[m * 36 + dd] = f2bf((acc[j][r] + bn) * scl);
        }
      }
      __syncthreads();
      const int m = tid & 63;
      const int hl = (tid >> 6) & 1;
      const int half = tid >> 7;
      const int M = m0 + m;
      const int b = M / WN;
      const int tok = M - b * WN;
      const int h = hh * 2 + hl;
      const unsigned short* L = hl ? Lh1 : Lh0;
      unsigned short* drow = dst + (((size_t)b * NH + h) * WN + tok) * HD + half * 16;
      *(short8*)&drow[0] = *(const short8*)&L[m * 36 + half * 16];
      *(short8*)&drow[8] = *(const short8*)&L[m * 36 + half * 16 + 8];
    }
    if (s < 2) {
      __syncthreads();          // all waves done reading Lh before DMA lands
      WSTAGE(B0, s + 1, 0);     // stage next slice's first W tile
      pipe_bar();
    }
  }
}

// ---------------- fused attention (r8 structure, unchanged): accl row-sum
// via 3rd PV MFMA (no shuffles), depth-2 pointer-increment bias/mask
// prefetch, setprio(1) around MFMA clusters. VGPR 40 -> 3 blocks/CU.
// NOTE: plain __launch_bounds__ — a min-waves arg makes the allocator spill.
__global__ __launch_bounds__(512) void attn_kernel(
    const unsigned short* __restrict__ qb, const unsigned short* __restrict__ kb,
    const unsigned short* __restrict__ vb, const uint32_t* __restrict__ biasP,
    const uint32_t* __restrict__ maskP, unsigned short* __restrict__ ob) {
  __shared__ __align__(16) unsigned short Ks[352][40];  // [perm key row][d]
  __shared__ __align__(16) unsigned short Vt[HD][360];  // [d][key]
  // XCD swizzle: bid%8 = XCD (observed round-robin); job groups of 24 share wdx
  const int bid = blockIdx.x;
  const int job = (bid & 7) * 96 + (bid >> 3);
  const int wdx = job / 24;
  const int inner = job - wdx * 24;
  const int h = inner >> 2;
  const int b = (inner & 3) * 32 + wdx;   // preserves wdx == b & 31
  const int tid = threadIdx.x;
  const int wave = tid >> 6, lane = tid & 63;
  const int quad = lane >> 4, c = lane & 15;
  const size_t base = ((size_t)b * NH + h) * (WN * HD);
  const unsigned short* q = qb + base;
  const unsigned short* k = kb + base;
  const unsigned short* v = vb + base;
  const uint32_t* bS = biasP + (size_t)h * BMSLICE;
  const uint32_t* mS = maskP + (size_t)wdx * BMSLICE;

  // stage K with permuted rows
  for (int t = tid; t < WN * 4; t += 512) {
    int r = t >> 2, ch = t & 3;
    int kk = r & 31;
    int row = (r & ~31) + 16 * ((kk >> 2) & 1) + 4 * (kk >> 3) + (kk & 3);
    *(short8*)&Ks[row][ch * 8] = *(const short8*)(k + r * HD + ch * 8);
  }
  for (int t = tid; t < 9 * 32; t += 512) {
    int kg = WN + (t >> 5);
    int kk = kg & 31;
    int row = (kg & ~31) + 16 * ((kk >> 2) & 1) + 4 * (kk >> 3) + (kk & 3);
    Ks[row][t & 31] = 0;
  }
  // stage V transposed, natural key order
  for (int t = tid; t < WN; t += 512) {
#pragma unroll
    for (int ch = 0; ch < 4; ++ch) {
      short8 vv = *(const short8*)(v + t * HD + ch * 8);
#pragma unroll
      for (int j = 0; j < 8; ++j) Vt[ch * 8 + j][t] = vv[j];
    }
  }
  for (int t = tid; t < 9 * 32; t += 512) {
    Vt[t & 31][WN + (t >> 5)] = 0;
  }
  __syncthreads();

  // bf16 ones fragment for the row-sum MFMA
  union { short8 v8; uint32_t d[4]; } on;
  on.d[0] = on.d[1] = on.d[2] = on.d[3] = 0x3F803F80u;

  for (int qt = wave; qt < 22; qt += 8) {
    const int q0 = qt * 16;
    int qr = q0 + c; if (qr > WN - 1) qr = WN - 1;
    const short8 qf = *(const short8*)(q + qr * HD + quad * 8);
    const uint32_t* bPtr = bS + ((size_t)quad * 352 + q0 + c) * 4;
    const uint32_t* mPtr = mS + ((size_t)quad * 352 + q0 + c) * 4;

    f32x4 o0 = (f32x4){0.f, 0.f, 0.f, 0.f};
    f32x4 o1 = (f32x4){0.f, 0.f, 0.f, 0.f};
    f32x4 accl = (f32x4){0.f, 0.f, 0.f, 0.f};
    uint4 bw = *(const uint4*)bPtr;
    uint4 mw = *(const uint4*)mPtr;
#pragma unroll 1
    for (int kc = 0; kc < 11; ++kc) {
      bPtr += BMKC; mPtr += BMKC;
      uint4 bwN = *(const uint4*)bPtr;   // kc=10: mapped garbage, unused
      uint4 mwN = *(const uint4*)mPtr;
      // C-operand = log2e*(bias+mask) for this lane's 8 keys
      f32x4 cc0, cc1;
      {
        __half2 s2; float2 f;
        s2 = __hadd2(*(__half2*)&bw.x, *(__half2*)&mw.x);
        f = __half22float2(s2); cc0[0] = f.x; cc1[0] = f.y;
        s2 = __hadd2(*(__half2*)&bw.y, *(__half2*)&mw.y);
        f = __half22float2(s2); cc0[1] = f.x; cc1[1] = f.y;
        s2 = __hadd2(*(__half2*)&bw.z, *(__half2*)&mw.z);
        f = __half22float2(s2); cc0[2] = f.x; cc1[2] = f.y;
        s2 = __hadd2(*(__half2*)&bw.w, *(__half2*)&mw.w);
        f = __half22float2(s2); cc0[3] = f.x; cc1[3] = f.y;
      }
      const int k0 = kc * 32;
      short8 kf0 = *(const short8*)&Ks[k0 + c][quad * 8];
      short8 kf1 = *(const short8*)&Ks[k0 + 16 + c][quad * 8];
      __builtin_amdgcn_s_setprio(1);
      f32x4 s0 = __builtin_amdgcn_mfma_f32_16x16x32_bf16(kf0, qf, cc0, 0, 0, 0);
      f32x4 s1 = __builtin_amdgcn_mfma_f32_16x16x32_bf16(kf1, qf, cc1, 0, 0, 0);
      __builtin_amdgcn_s_setprio(0);
      // scores in log2 domain -> direct v_exp_f32 (2^x), unnormalized;
      // OOB keys carry -30000 -> exp2==0
      float p0 = __builtin_amdgcn_exp2f(s0[0]), p1 = __builtin_amdgcn_exp2f(s0[1]);
      float p2 = __builtin_amdgcn_exp2f(s0[2]), p3 = __builtin_amdgcn_exp2f(s0[3]);
      float p4 = __builtin_amdgcn_exp2f(s1[0]), p5 = __builtin_amdgcn_exp2f(s1[1]);
      float p6 = __builtin_amdgcn_exp2f(s1[2]), p7 = __builtin_amdgcn_exp2f(s1[3]);
      union { short8 v8; uint32_t d[4]; } pf;
      pf.d[0] = pk2bf(p0, p1);
      pf.d[1] = pk2bf(p2, p3);
      pf.d[2] = pk2bf(p4, p5);
      pf.d[3] = pk2bf(p6, p7);
      short8 vf0 = *(const short8*)&Vt[c][k0 + quad * 8];
      short8 vf1 = *(const short8*)&Vt[16 + c][k0 + quad * 8];
      __builtin_amdgcn_s_setprio(1);
      o0 = __builtin_amdgcn_mfma_f32_16x16x32_bf16(pf.v8, vf0, o0, 0, 0, 0);
      o1 = __builtin_amdgcn_mfma_f32_16x16x32_bf16(pf.v8, vf1, o1, 0, 0, 0);
      accl = __builtin_amdgcn_mfma_f32_16x16x32_bf16(pf.v8, on.v8, accl, 0, 0, 0);
      __builtin_amdgcn_s_setprio(0);
      bw = bwN; mw = mwN;
    }

    // Epilogue: O rows m=quad*4+r are queries q0+m; accl[r] = l for that
    // query at the SAME lane (no shuffles). Store into swizzled tile layout:
    // tile (M>>7, kt=h), row M&127, chunk lch ^ ((row>>1)&3) -- proj reads
    // via global_load_lds.
#pragma unroll
    for (int r = 0; r < 4; ++r) {
      int n = q0 + quad * 4 + r;
      if (n < WN) {
        float inv = 1.0f / accl[r];
        int M = b * WN + n;
        int rloc = M & 127;
        int xr2 = (rloc >> 1) & 3;
        size_t base2 = (((size_t)(M >> 7) * 6 + h) << 12) + rloc * 32;
        ob[base2 + (((c >> 3) ^ xr2) << 3) + (c & 7)] = f2bf(o0[r] * inv);
        ob[base2 + ((((c >> 3) | 2) ^ xr2) << 3) + (c & 7)] = f2bf(o1[r] * inv);
      }
    }
  }
}

// ---------------- output projection (r8 structure, unchanged): 2-phase
// pipeline, 32KB LDS; obuf (written swizzled by attn) and pre-swizzled wpb
// staged via global_load_lds width-16; fp32 out.
__global__ __launch_bounds__(256) void proj_kernel(
    const unsigned short* __restrict__ obp, const unsigned short* __restrict__ wpb,
    const float* __restrict__ bvec, float* __restrict__ out) {
  __shared__ __align__(16) unsigned short SL[16384];   // 32KB, two 8192 bufs
  const int tid = threadIdx.x;
  const int wave = tid >> 6, lane = tid & 63;
  const int quad = lane >> 4, c = lane & 15;
  const int m0 = blockIdx.x * 64;
  const int mb = blockIdx.x >> 1;
  const int r0 = (blockIdx.x & 1) * 64;
  const int chk = (quad ^ ((c >> 1) & 3)) * 8;

  f32x4 acc[12];
#pragma unroll
  for (int j = 0; j < 12; ++j) acc[j] = (f32x4){0.f, 0.f, 0.f, 0.f};

  auto STAGE = [&](unsigned short* buf, int kt) {
    const unsigned short* gx =
        obp + (((size_t)mb * 6 + kt) << 12) + r0 * 32 + tid * 8;
    const unsigned short* gw = wpb + (size_t)kt * 6144 + tid * 8;
    unsigned short* lx = buf + (size_t)wave * 512;          // XL: 2048 shorts
    unsigned short* lw = buf + 2048 + (size_t)wave * 512;   // WL: 6144 shorts
    gload16(gx, lx);
    gload16(gw, lw);
    gload16(gw + 2048, lw + 2048);
    gload16(gw + 4096, lw + 4096);
  };
  auto COMPUTE = [&](const unsigned short* buf) {
    const unsigned short* XLb = buf;
    const unsigned short* WLb = buf + 2048;
    short8 af = *(const short8*)&XLb[(wave * 16 + c) * 32 + chk];
#pragma unroll
    for (int j = 0; j < 12; ++j) {
      short8 bfr = *(const short8*)&WLb[(j * 16 + c) * 32 + chk];
      acc[j] = __builtin_amdgcn_mfma_f32_16x16x32_bf16(af, bfr, acc[j], 0, 0, 0);
    }
  };

  unsigned short* B0 = SL;
  unsigned short* B1 = SL + 8192;
  STAGE(B0, 0);
  pipe_bar();
#pragma unroll
  for (int p = 0; p < 3; ++p) {
    STAGE(B1, 2 * p + 1);
    COMPUTE(B0);
    pipe_bar();
    if (p < 2) STAGE(B0, 2 * p + 2);
    COMPUTE(B1);
    pipe_bar();
  }

#pragma unroll
  for (int j = 0; j < 12; ++j) {
    int col = j * 16 + c;
    float bn = bvec[col];
#pragma unroll
    for (int r = 0; r < 4; ++r) {
      int m = m0 + wave * 16 + quad * 4 + r;
      out[(size_t)m * CD + col] = acc[j][r] + bn;
    }
  }
}

extern "C" void kernel_launch(void* const* d_in, const int* in_sizes, int n_in,
                              void* d_out, int out_size, void* d_ws, size_t ws_size,
                              hipStream_t stream) {
  const float* x      = (const float*)d_in[0];
  const float* mask   = (const float*)d_in[1];
  const float* qkv_w  = (const float*)d_in[2];
  const float* qkv_b  = (const float*)d_in[3];
  const float* proj_w = (const float*)d_in[4];
  const float* proj_b = (const float*)d_in[5];
  const float* rpb    = (const float*)d_in[6];
  const int*   rel    = (const int*)d_in[7];
  float* out = (float*)d_out;

  char* ws = (char*)d_ws;
  uint32_t* biasP = (uint32_t*)ws;                       // 6*61952*4 = 1,486,848
  size_t off = 1486848;
  uint32_t* maskP = (uint32_t*)(ws + off); off += 7929856;   // 32*61952*4
  unsigned short* qb = (unsigned short*)(ws + off); off += 16859136;
  unsigned short* kb = (unsigned short*)(ws + off); off += 16859136;
  unsigned short* vb = (unsigned short*)(ws + off); off += 16859136;
  unsigned short* wqb = (unsigned short*)(ws + off); off += 221184;
  unsigned short* wpb = (unsigned short*)(ws + off); off += 73728;
  unsigned short* obuf = (unsigned short*)(ws + off); off += 16859136;

  hipLaunchKernelGGL(prep_kernel, dim3(264 + 352 + 54 + 18), dim3(256),
                     0, stream,
                     qkv_w, proj_w, wqb, wpb, rel, rpb, mask, biasP, maskP);
  hipLaunchKernelGGL(qkv_kernel, dim3(686), dim3(256), 0, stream,
                     x, wqb, qkv_b, qb, kb, vb);
  hipLaunchKernelGGL(attn_kernel, dim3(NH * NB), dim3(512), 0, stream,
                     qb, kb, vb, biasP, maskP, obuf);
  hipLaunchKernelGGL(proj_kernel, dim3(686), dim3(256), 0, stream,
                     obuf, wpb, proj_b, out);
}

// Round 12
// 191.534 us; speedup vs baseline: 1.0844x; 1.0844x over previous
//
#include <hip/hip_runtime.h>
#include <hip/hip_fp16.h>
#include <hip/hip_bf16.h>
#include <stdint.h>

#define WN 343       // tokens per window
#define NH 6         // heads
#define HD 32        // head dim
#define CD 192       // channels
#define NB 128       // windows (batch)
#define NWM 32       // mask windows
#define BMROW 352            // padded query dim
#define BMSLICE (11*16*BMROW) // dwords per slice = 61952
#define BMKC (16*BMROW)       // dwords per kc chunk = 5632
#define LOG2E 1.4426950408889634f
#define XTS 2064     // X LDS tile stride in shorts (64*32 + 16 stagger)

typedef __attribute__((ext_vector_type(8))) short short8;
typedef __attribute__((ext_vector_type(4))) float f32x4;

__device__ __forceinline__ unsigned short f2bf(float f) {
  union { float f; uint32_t u; } v; v.f = f;
  uint32_t r = v.u + 0x7fffu + ((v.u >> 16) & 1u);
  return (unsigned short)(r >> 16);
}

// packed f32x2 -> bf16x2 (v_cvt_pk_bf16_f32 on gfx950); low half = a
__device__ __forceinline__ uint32_t pk2bf(float a, float b) {
  __hip_bfloat162 h = __float22bfloat162_rn(make_float2(a, b));
  return *(uint32_t*)&h;
}

__device__ __forceinline__ uint32_t pkh2(float a, float b) {
  __half2 h; h.x = __float2half(a); h.y = __float2half(b);
  return *(uint32_t*)&h;
}

// async global->LDS, 16B per lane; LDS dest is wave-uniform base + lane*16
typedef const __attribute__((address_space(1))) unsigned int* gas_ptr;
typedef __attribute__((address_space(3))) unsigned int* las_ptr;
__device__ __forceinline__ void gload16(const unsigned short* g, unsigned short* l) {
  __builtin_amdgcn_global_load_lds((gas_ptr)(const void*)g, (las_ptr)(void*)l, 16, 0, 0);
}

// 2-phase pipeline barrier (T3 minimal): manual vmcnt drain + RAW s_barrier.
// sched_barrier(0) fences (rule #18: hipcc hoists past inline asm).
__device__ __forceinline__ void pipe_bar() {
  asm volatile("s_waitcnt vmcnt(0) lgkmcnt(0)" ::: "memory");
  __builtin_amdgcn_sched_barrier(0);
  __builtin_amdgcn_s_barrier();
  __builtin_amdgcn_sched_barrier(0);
}

// ---------------- prep_w (r12): ONLY the wq swizzle (54 blocks) -- the sole
// prep output qkv itself depends on. All other prep branches (bias gather,
// mask repack, wp swizzle) feed LATER kernels and now ride inside the qkv
// launch as extra blocks, filling its idle latency slots instead of
// occupying a serialized stage.
__global__ __launch_bounds__(256) void prep_w_kernel(
    const float* __restrict__ wq, unsigned short* __restrict__ wqb) {
  // wq -> swizzled bf16 tiles: 18 tiles (s*6+kt) x 192 rows x 4 chunks
  int g = blockIdx.x * 256 + threadIdx.x;   // < 13824
  int sk = g / 768; int rem = g - sk * 768;
  int row = rem >> 2; int cc = rem & 3;
  int s = sk / 6; int kt = sk - s * 6;
  int lch = cc ^ ((row >> 1) & 3);
  const float* src = wq + (size_t)(s * 192 + row) * CD + kt * 32 + lch * 8;
  f32x4 a = *(const f32x4*)src;
  f32x4 b = *(const f32x4*)(src + 4);
  union { short8 v8; uint32_t d[4]; } pk;
  pk.d[0] = pk2bf(a[0], a[1]);
  pk.d[1] = pk2bf(a[2], a[3]);
  pk.d[2] = pk2bf(b[0], b[1]);
  pk.d[3] = pk2bf(b[2], b[3]);
  *(short8*)(wqb + (size_t)g * 8) = pk.v8;
}

// ---------------- QKV GEMM + merged prep (r12): grid 1320.
// Blocks 0-685: r11 qkv (64 rows x all 3 slices, X staged once, W dbuf via
// global_load_lds, 2-phase pipe_bar). Blocks 686-949: bias gather (feeds
// attn). Blocks 950-1301: mask repack, XCD-ALIGNED -- block's bid&7 ==
// wdx>>2, matching attn's consumer mapping, so slices are produced into the
// L2 that reads them. Blocks 1302-1319: wp swizzle (feeds proj). The merged
// branches run concurrent with qkv's latency-bound blocks (qkv counters:
// 10% VALU, 18% HBM -- plenty idle). bias branch aliases its 11.6KB scratch
// onto the qkv LDS.
__global__ __launch_bounds__(256) void qkv_kernel(
    const float* __restrict__ x, const unsigned short* __restrict__ wqb,
    const float* __restrict__ bvec,
    unsigned short* __restrict__ qb, unsigned short* __restrict__ kb,
    unsigned short* __restrict__ vb,
    const int* __restrict__ rel, const float* __restrict__ rpb,
    const float* __restrict__ mask, uint32_t* __restrict__ bP,
    uint32_t* __restrict__ mP,
    const float* __restrict__ wp, unsigned short* __restrict__ wpb) {
  __shared__ __align__(16) unsigned short SL[6 * XTS + 2 * 6144];  // 48.4KB
  const int bid = blockIdx.x;
  const int tid = threadIdx.x;

  if (bid < 686) {
    // ================= qkv GEMM branch (r11, unchanged) =================
    unsigned short* B0 = SL + 6 * XTS;
    unsigned short* B1 = B0 + 6144;
    const int wave = tid >> 6, lane = tid & 63;
    const int quad = lane >> 4, c = lane & 15;
    const int m0 = bid * 64;
    const int chk = (quad ^ ((c >> 1) & 3)) * 8;

    auto WSTAGE = [&](unsigned short* buf, int s, int kt) {
      const unsigned short* gw = wqb + ((size_t)s * 6 + kt) * 6144 + tid * 8;
      unsigned short* lw = buf + (size_t)wave * 512;
      gload16(gw, lw);
      gload16(gw + 2048, lw + 2048);
      gload16(gw + 4096, lw + 4096);
    };

    // stage W(0,0) DMA first (overlaps the X cvt), then X once: 64x192
    // fp32 -> bf16 into per-kt tiles [64][32] with XOR-swizzled 16B chunks
    WSTAGE(B0, 0, 0);
#pragma unroll
    for (int it = 0; it < 6; ++it) {
      int u = tid + 256 * it;              // < 1536
      int lrow = u / 24, c24 = u - lrow * 24;
      int kt = c24 >> 2, j = c24 & 3;
      const float* src = x + (size_t)(m0 + lrow) * CD + kt * 32 + j * 8;
      f32x4 a = *(const f32x4*)src;
      f32x4 b = *(const f32x4*)(src + 4);
      union { short8 v8; uint32_t d[4]; } pk;
      pk.d[0] = pk2bf(a[0], a[1]);
      pk.d[1] = pk2bf(a[2], a[3]);
      pk.d[2] = pk2bf(b[0], b[1]);
      pk.d[3] = pk2bf(b[2], b[3]);
      int cw = (j ^ ((lrow >> 1) & 3)) * 8;
      *(short8*)&SL[kt * XTS + lrow * 32 + cw] = pk.v8;
    }
    pipe_bar();

    // q scale folded with log2(e): 32^-0.5 * 1.4426950409 (softmax runs in
    // exp2 domain; bias/mask pre-scaled by log2(e) in the merged branches)
    const float qscale = 0.25503486f;
    f32x4 acc[12];
    // repack overlays the W dbuf region; stride 36 shorts -> all-32-bank
    unsigned short* Lh0 = B0;            // 64 rows x 36
    unsigned short* Lh1 = B0 + 2304;

    for (int s = 0; s < 3; ++s) {
#pragma unroll
      for (int j = 0; j < 12; ++j) acc[j] = (f32x4){0.f, 0.f, 0.f, 0.f};

      for (int kt = 0; kt < 6; ++kt) {
        unsigned short* cur = (kt & 1) ? B1 : B0;
        unsigned short* nxt = (kt & 1) ? B0 : B1;
        if (kt < 5) WSTAGE(nxt, s, kt + 1);   // issue next W while computing
        const unsigned short* XLb = SL + kt * XTS;
        short8 af = *(const short8*)&XLb[(wave * 16 + c) * 32 + chk];
#pragma unroll
        for (int j = 0; j < 12; ++j) {
          short8 bfr = *(const short8*)&cur[(j * 16 + c) * 32 + chk];
          acc[j] = __builtin_amdgcn_mfma_f32_16x16x32_bf16(af, bfr, acc[j], 0, 0, 0);
        }
        pipe_bar();
      }

      // epilogue for slice s (repack buffers live in the W dbuf region)
      unsigned short* dst = (s == 0) ? qb : ((s == 1) ? kb : vb);
      const float scl = (s == 0) ? qscale : 1.0f;
      const int n0 = s * 192;
      for (int hh = 0; hh < 3; ++hh) {
        __syncthreads();
#pragma unroll
        for (int jj = 0; jj < 4; ++jj) {
          int j = hh * 4 + jj;
          int hl = jj >> 1;
          int dd = (jj & 1) * 16 + c;
          float bn = bvec[n0 + j * 16 + c];
          unsigned short* L = hl ? Lh1 : Lh0;
#pragma unroll
          for (int r = 0; r < 4; ++r) {
            int m = wave * 16 + quad * 4 + r;
            L[m * 36 + dd] = f2bf((acc[j][r] + bn) * scl);
          }
        }
        __syncthreads();
        const int m = tid & 63;
        const int hl = (tid >> 6) & 1;
        const int half = tid >> 7;
        const int M = m0 + m;
        const int b = M / WN;
        const int tok = M - b * WN;
        const int h = hh * 2 + hl;
        const unsigned short* L = hl ? Lh1 : Lh0;
        unsigned short* drow = dst + (((size_t)b * NH + h) * WN + tok) * HD + half * 16;
        *(short8*)&drow[0] = *(const short8*)&L[m * 36 + half * 16];
        *(short8*)&drow[8] = *(const short8*)&L[m * 36 + half * 16 + 8];
      }
      if (s < 2) {
        __syncthreads();          // all waves done reading Lh before DMA lands
        WSTAGE(B0, s + 1, 0);     // stage next slice's first W tile
        pipe_bar();
      }
    }
    return;
  }

  int cb = bid - 686;
  if (cb < 264) {
    // ========== bias gather: 66 (h,kc) pairs x 4 row-groups of 88 ==========
    float (*M)[33] = (float (*)[33])&SL[0];   // 11.6KB, aliases qkv LDS
    const int h = cb / 44;
    const int rem = cb - h * 44;
    const int kc = rem >> 2;
    const int g = rem & 3;
    const int n0 = g * 88;
    const int k0 = kc * 32;
    for (int idx = tid; idx < 88 * 32; idx += 256) {
      int nl = idx >> 5, k = idx & 31;
      int n = n0 + nl;
      int nc = (n < WN) ? n : (WN - 1);
      M[nl][k] = (k0 + k < WN) ? rpb[rel[nc * WN + k0 + k] * NH + h] * LOG2E
                               : -30000.0f;
    }
    __syncthreads();
    uint32_t* outp = bP + (size_t)h * BMSLICE + (size_t)kc * BMKC;
    if (tid < 88) {
      const int nl = tid;
      const int n = n0 + nl;
#pragma unroll
      for (int quad = 0; quad < 4; ++quad) {
        uint4 o;
        o.x = pkh2(M[nl][quad * 8 + 0], M[nl][quad * 8 + 4]);
        o.y = pkh2(M[nl][quad * 8 + 1], M[nl][quad * 8 + 5]);
        o.z = pkh2(M[nl][quad * 8 + 2], M[nl][quad * 8 + 6]);
        o.w = pkh2(M[nl][quad * 8 + 3], M[nl][quad * 8 + 7]);
        *(uint4*)(outp + ((size_t)quad * 352 + n) * 4) = o;
      }
    }
    return;
  }
  cb -= 264;
  if (cb < 352) {
    // ========== mask repack, LDS-free, XCD-aligned ==========
    // bid&7 (observed XCD round-robin) == wdx>>2, matching attn's consumer
    // mapping (attn XCD x reads wdx in [4x, 4x+4)). j -> (g,t) bijective:
    // g = bid&7, t = j>>3 in [0,44); wdx = 4g + t/11, kc = t%11.
    const int g = bid & 7;
    const int t = cb >> 3;
    const int wdx = 4 * g + t / 11;
    const int kc = t - 11 * (t / 11);
    const int k0 = kc * 32;
    const float* mw = mask + (size_t)wdx * (WN * WN);
    uint32_t* outp = mP + (size_t)wdx * BMSLICE + (size_t)kc * BMKC;
#pragma unroll
    for (int quad = 0; quad < 4; ++quad) {
      const int q8 = quad * 8;
#pragma unroll
      for (int j = 0; j < 2; ++j) {
        int n = tid + 256 * j;
        if (n < 352) {
          float v[8];
#pragma unroll
          for (int i = 0; i < 8; ++i) {
            int kk = k0 + q8 + i;
            v[i] = (n < WN && kk < WN) ? mw[n * WN + kk] * LOG2E : 0.0f;
          }
          uint4 o;
          o.x = pkh2(v[0], v[4]);
          o.y = pkh2(v[1], v[5]);
          o.z = pkh2(v[2], v[6]);
          o.w = pkh2(v[3], v[7]);
          *(uint4*)(outp + ((size_t)quad * 352 + n) * 4) = o;
        }
      }
    }
    return;
  }
  cb -= 352;
  // ========== wp -> swizzled bf16 tiles (18 blocks, feeds proj) ==========
  int g = cb * 256 + tid;            // < 4608
  int kt = g / 768; int rem = g - kt * 768;
  int row = rem >> 2; int cc = rem & 3;
  int lch = cc ^ ((row >> 1) & 3);
  const float* src = wp + (size_t)row * CD + kt * 32 + lch * 8;
  f32x4 a = *(const f32x4*)src;
  f32x4 b = *(const f32x4*)(src + 4);
  union { short8 v8; uint32_t d[4]; } pk;
  pk.d[0] = pk2bf(a[0], a[1]);
  pk.d[1] = pk2bf(a[2], a[3]);
  pk.d[2] = pk2bf(b[0], b[1]);
  pk.d[3] = pk2bf(b[2], b[3]);
  *(short8*)(wpb + (size_t)g * 8) = pk.v8;
}

// ---------------- fused attention (r8 structure, unchanged): accl row-sum
// via 3rd PV MFMA (no shuffles), depth-2 pointer-increment bias/mask
// prefetch, setprio(1) around MFMA clusters. VGPR 40 -> 3 blocks/CU.
// NOTE: plain __launch_bounds__ — a min-waves arg makes the allocator spill.
__global__ __launch_bounds__(512) void attn_kernel(
    const unsigned short* __restrict__ qb, const unsigned short* __restrict__ kb,
    const unsigned short* __restrict__ vb, const uint32_t* __restrict__ biasP,
    const uint32_t* __restrict__ maskP, unsigned short* __restrict__ ob) {
  __shared__ __align__(16) unsigned short Ks[352][40];  // [perm key row][d]
  __shared__ __align__(16) unsigned short Vt[HD][360];  // [d][key]
  // XCD swizzle: bid%8 = XCD (observed round-robin); job groups of 24 share wdx
  const int bid = blockIdx.x;
  const int job = (bid & 7) * 96 + (bid >> 3);
  const int wdx = job / 24;
  const int inner = job - wdx * 24;
  const int h = inner >> 2;
  const int b = (inner & 3) * 32 + wdx;   // preserves wdx == b & 31
  const int tid = threadIdx.x;
  const int wave = tid >> 6, lane = tid & 63;
  const int quad = lane >> 4, c = lane & 15;
  const size_t base = ((size_t)b * NH + h) * (WN * HD);
  const unsigned short* q = qb + base;
  const unsigned short* k = kb + base;
  const unsigned short* v = vb + base;
  const uint32_t* bS = biasP + (size_t)h * BMSLICE;
  const uint32_t* mS = maskP + (size_t)wdx * BMSLICE;

  // stage K with permuted rows
  for (int t = tid; t < WN * 4; t += 512) {
    int r = t >> 2, ch = t & 3;
    int kk = r & 31;
    int row = (r & ~31) + 16 * ((kk >> 2) & 1) + 4 * (kk >> 3) + (kk & 3);
    *(short8*)&Ks[row][ch * 8] = *(const short8*)(k + r * HD + ch * 8);
  }
  for (int t = tid; t < 9 * 32; t += 512) {
    int kg = WN + (t >> 5);
    int kk = kg & 31;
    int row = (kg & ~31) + 16 * ((kk >> 2) & 1) + 4 * (kk >> 3) + (kk & 3);
    Ks[row][t & 31] = 0;
  }
  // stage V transposed, natural key order
  for (int t = tid; t < WN; t += 512) {
#pragma unroll
    for (int ch = 0; ch < 4; ++ch) {
      short8 vv = *(const short8*)(v + t * HD + ch * 8);
#pragma unroll
      for (int j = 0; j < 8; ++j) Vt[ch * 8 + j][t] = vv[j];
    }
  }
  for (int t = tid; t < 9 * 32; t += 512) {
    Vt[t & 31][WN + (t >> 5)] = 0;
  }
  __syncthreads();

  // bf16 ones fragment for the row-sum MFMA
  union { short8 v8; uint32_t d[4]; } on;
  on.d[0] = on.d[1] = on.d[2] = on.d[3] = 0x3F803F80u;

  for (int qt = wave; qt < 22; qt += 8) {
    const int q0 = qt * 16;
    int qr = q0 + c; if (qr > WN - 1) qr = WN - 1;
    const short8 qf = *(const short8*)(q + qr * HD + quad * 8);
    const uint32_t* bPtr = bS + ((size_t)quad * 352 + q0 + c) * 4;
    const uint32_t* mPtr = mS + ((size_t)quad * 352 + q0 + c) * 4;

    f32x4 o0 = (f32x4){0.f, 0.f, 0.f, 0.f};
    f32x4 o1 = (f32x4){0.f, 0.f, 0.f, 0.f};
    f32x4 accl = (f32x4){0.f, 0.f, 0.f, 0.f};
    uint4 bw = *(const uint4*)bPtr;
    uint4 mw = *(const uint4*)mPtr;
#pragma unroll 1
    for (int kc = 0; kc < 11; ++kc) {
      bPtr += BMKC; mPtr += BMKC;
      uint4 bwN = *(const uint4*)bPtr;   // kc=10: mapped garbage, unused
      uint4 mwN = *(const uint4*)mPtr;
      // C-operand = log2e*(bias+mask) for this lane's 8 keys
      f32x4 cc0, cc1;
      {
        __half2 s2; float2 f;
        s2 = __hadd2(*(__half2*)&bw.x, *(__half2*)&mw.x);
        f = __half22float2(s2); cc0[0] = f.x; cc1[0] = f.y;
        s2 = __hadd2(*(__half2*)&bw.y, *(__half2*)&mw.y);
        f = __half22float2(s2); cc0[1] = f.x; cc1[1] = f.y;
        s2 = __hadd2(*(__half2*)&bw.z, *(__half2*)&mw.z);
        f = __half22float2(s2); cc0[2] = f.x; cc1[2] = f.y;
        s2 = __hadd2(*(__half2*)&bw.w, *(__half2*)&mw.w);
        f = __half22float2(s2); cc0[3] = f.x; cc1[3] = f.y;
      }
      const int k0 = kc * 32;
      short8 kf0 = *(const short8*)&Ks[k0 + c][quad * 8];
      short8 kf1 = *(const short8*)&Ks[k0 + 16 + c][quad * 8];
      __builtin_amdgcn_s_setprio(1);
      f32x4 s0 = __builtin_amdgcn_mfma_f32_16x16x32_bf16(kf0, qf, cc0, 0, 0, 0);
      f32x4 s1 = __builtin_amdgcn_mfma_f32_16x16x32_bf16(kf1, qf, cc1, 0, 0, 0);
      __builtin_amdgcn_s_setprio(0);
      // scores in log2 domain -> direct v_exp_f32 (2^x), unnormalized;
      // OOB keys carry -30000 -> exp2==0
      float p0 = __builtin_amdgcn_exp2f(s0[0]), p1 = __builtin_amdgcn_exp2f(s0[1]);
      float p2 = __builtin_amdgcn_exp2f(s0[2]), p3 = __builtin_amdgcn_exp2f(s0[3]);
      float p4 = __builtin_amdgcn_exp2f(s1[0]), p5 = __builtin_amdgcn_exp2f(s1[1]);
      float p6 = __builtin_amdgcn_exp2f(s1[2]), p7 = __builtin_amdgcn_exp2f(s1[3]);
      union { short8 v8; uint32_t d[4]; } pf;
      pf.d[0] = pk2bf(p0, p1);
      pf.d[1] = pk2bf(p2, p3);
      pf.d[2] = pk2bf(p4, p5);
      pf.d[3] = pk2bf(p6, p7);
      short8 vf0 = *(const short8*)&Vt[c][k0 + quad * 8];
      short8 vf1 = *(const short8*)&Vt[16 + c][k0 + quad * 8];
      __builtin_amdgcn_s_setprio(1);
      o0 = __builtin_amdgcn_mfma_f32_16x16x32_bf16(pf.v8, vf0, o0, 0, 0, 0);
      o1 = __builtin_amdgcn_mfma_f32_16x16x32_bf16(pf.v8, vf1, o1, 0, 0, 0);
      accl = __builtin_amdgcn_mfma_f32_16x16x32_bf16(pf.v8, on.v8, accl, 0, 0, 0);
      __builtin_amdgcn_s_setprio(0);
      bw = bwN; mw = mwN;
    }

    // Epilogue: O rows m=quad*4+r are queries q0+m; accl[r] = l for that
    // query at the SAME lane (no shuffles). Store into swizzled tile layout:
    // tile (M>>7, kt=h), row M&127, chunk lch ^ ((row>>1)&3) -- proj reads
    // via global_load_lds.
#pragma unroll
    for (int r = 0; r < 4; ++r) {
      int n = q0 + quad * 4 + r;
      if (n < WN) {
        float inv = 1.0f / accl[r];
        int M = b * WN + n;
        int rloc = M & 127;
        int xr2 = (rloc >> 1) & 3;
        size_t base2 = (((size_t)(M >> 7) * 6 + h) << 12) + rloc * 32;
        ob[base2 + (((c >> 3) ^ xr2) << 3) + (c & 7)] = f2bf(o0[r] * inv);
        ob[base2 + ((((c >> 3) | 2) ^ xr2) << 3) + (c & 7)] = f2bf(o1[r] * inv);
      }
    }
  }
}

// ---------------- output projection (r8 structure, unchanged): 2-phase
// pipeline, 32KB LDS; obuf (written swizzled by attn) and pre-swizzled wpb
// staged via global_load_lds width-16; fp32 out.
__global__ __launch_bounds__(256) void proj_kernel(
    const unsigned short* __restrict__ obp, const unsigned short* __restrict__ wpb,
    const float* __restrict__ bvec, float* __restrict__ out) {
  __shared__ __align__(16) unsigned short SL[16384];   // 32KB, two 8192 bufs
  const int tid = threadIdx.x;
  const int wave = tid >> 6, lane = tid & 63;
  const int quad = lane >> 4, c = lane & 15;
  const int m0 = blockIdx.x * 64;
  const int mb = blockIdx.x >> 1;
  const int r0 = (blockIdx.x & 1) * 64;
  const int chk = (quad ^ ((c >> 1) & 3)) * 8;

  f32x4 acc[12];
#pragma unroll
  for (int j = 0; j < 12; ++j) acc[j] = (f32x4){0.f, 0.f, 0.f, 0.f};

  auto STAGE = [&](unsigned short* buf, int kt) {
    const unsigned short* gx =
        obp + (((size_t)mb * 6 + kt) << 12) + r0 * 32 + tid * 8;
    const unsigned short* gw = wpb + (size_t)kt * 6144 + tid * 8;
    unsigned short* lx = buf + (size_t)wave * 512;          // XL: 2048 shorts
    unsigned short* lw = buf + 2048 + (size_t)wave * 512;   // WL: 6144 shorts
    gload16(gx, lx);
    gload16(gw, lw);
    gload16(gw + 2048, lw + 2048);
    gload16(gw + 4096, lw + 4096);
  };
  auto COMPUTE = [&](const unsigned short* buf) {
    const unsigned short* XLb = buf;
    const unsigned short* WLb = buf + 2048;
    short8 af = *(const short8*)&XLb[(wave * 16 + c) * 32 + chk];
#pragma unroll
    for (int j = 0; j < 12; ++j) {
      short8 bfr = *(const short8*)&WLb[(j * 16 + c) * 32 + chk];
      acc[j] = __builtin_amdgcn_mfma_f32_16x16x32_bf16(af, bfr, acc[j], 0, 0, 0);
    }
  };

  unsigned short* B0 = SL;
  unsigned short* B1 = SL + 8192;
  STAGE(B0, 0);
  pipe_bar();
#pragma unroll
  for (int p = 0; p < 3; ++p) {
    STAGE(B1, 2 * p + 1);
    COMPUTE(B0);
    pipe_bar();
    if (p < 2) STAGE(B0, 2 * p + 2);
    COMPUTE(B1);
    pipe_bar();
  }

#pragma unroll
  for (int j = 0; j < 12; ++j) {
    int col = j * 16 + c;
    float bn = bvec[col];
#pragma unroll
    for (int r = 0; r < 4; ++r) {
      int m = m0 + wave * 16 + quad * 4 + r;
      out[(size_t)m * CD + col] = acc[j][r] + bn;
    }
  }
}

extern "C" void kernel_launch(void* const* d_in, const int* in_sizes, int n_in,
                              void* d_out, int out_size, void* d_ws, size_t ws_size,
                              hipStream_t stream) {
  const float* x      = (const float*)d_in[0];
  const float* mask   = (const float*)d_in[1];
  const float* qkv_w  = (const float*)d_in[2];
  const float* qkv_b  = (const float*)d_in[3];
  const float* proj_w = (const float*)d_in[4];
  const float* proj_b = (const float*)d_in[5];
  const float* rpb    = (const float*)d_in[6];
  const int*   rel    = (const int*)d_in[7];
  float* out = (float*)d_out;

  char* ws = (char*)d_ws;
  uint32_t* biasP = (uint32_t*)ws;                       // 6*61952*4 = 1,486,848
  size_t off = 1486848;
  uint32_t* maskP = (uint32_t*)(ws + off); off += 7929856;   // 32*61952*4
  unsigned short* qb = (unsigned short*)(ws + off); off += 16859136;
  unsigned short* kb = (unsigned short*)(ws + off); off += 16859136;
  unsigned short* vb = (unsigned short*)(ws + off); off += 16859136;
  unsigned short* wqb = (unsigned short*)(ws + off); off += 221184;
  unsigned short* wpb = (unsigned short*)(ws + off); off += 73728;
  unsigned short* obuf = (unsigned short*)(ws + off); off += 16859136;

  hipLaunchKernelGGL(prep_w_kernel, dim3(54), dim3(256), 0, stream,
                     qkv_w, wqb);
  hipLaunchKernelGGL(qkv_kernel, dim3(686 + 264 + 352 + 18), dim3(256), 0, stream,
                     x, wqb, qkv_b, qb, kb, vb,
                     rel, rpb, mask, biasP, maskP, proj_w, wpb);
  hipLaunchKernelGGL(attn_kernel, dim3(NH * NB), dim3(512), 0, stream,
                     qb, kb, vb, biasP, maskP, obuf);
  hipLaunchKernelGGL(proj_kernel, dim3(686), dim3(256), 0, stream,
                     obuf, wpb, proj_b, out);
}